// Round 1
// baseline (194.319 us; speedup 1.0000x reference)
//
#include <hip/hip_runtime.h>

typedef __bf16 bf16x8 __attribute__((ext_vector_type(8)));
typedef float f32x4 __attribute__((ext_vector_type(4)));

// Repack W [H=128][K] fp32 -> bf16 MFMA B-fragments.
// Fragment layout: dst[((ks*8 + n)*64 + lane)*8 + e] = bf16(W[n*16 + (lane&15)][ks*32 + (lane>>4)*8 + e])
__global__ void prep_w_kernel(const float* __restrict__ W, __bf16* __restrict__ dst,
                              int K, int total) {
    int t = blockIdx.x * blockDim.x + threadIdx.x;
    if (t >= total) return;
    int lane = t & 63;
    int n = (t >> 6) & 7;
    int ks = t >> 9;
    int row = n * 16 + (lane & 15);
    int k0 = ks * 32 + ((lane >> 4) << 3);
    const float* src = W + (size_t)row * K + k0;
    __bf16* d = dst + (size_t)t * 8;
#pragma unroll
    for (int e = 0; e < 8; ++e) d[e] = (__bf16)src[e];
}

// One block = 256 threads = 4 waves; block computes 128 rows x 128 cols.
// Each wave: 32 rows (2 M-frags) x 128 cols (8 N-frags), K-loop of 16x16x32 MFMAs.
template <int K>
__global__ __launch_bounds__(256, 2) void node_linear_kernel(
    const float* __restrict__ x, const __bf16* __restrict__ Bfrag,
    const float* __restrict__ bias, const int* __restrict__ idx,
    float* __restrict__ out, int M)
{
    constexpr int KSTEPS = K / 32;
    const int lane = threadIdx.x & 63;
    const int wave = threadIdx.x >> 6;
    const int l15 = lane & 15;
    const int kg = lane >> 4;
    const int rowbase = blockIdx.x * 128 + wave * 32;

    f32x4 acc[2][8] = {};

    // A rows owned by this lane (clamped for the tail block; stores are guarded)
    int r0 = rowbase + l15;
    int r1 = r0 + 16;
    int r0c = r0 < M ? r0 : M - 1;
    int r1c = r1 < M ? r1 : M - 1;
    const float* a0p = x + (size_t)r0c * K + kg * 8;
    const float* a1p = x + (size_t)r1c * K + kg * 8;
    const bf16x8* bbase = reinterpret_cast<const bf16x8*>(Bfrag) + lane;

#pragma unroll
    for (int ks = 0; ks < KSTEPS; ++ks) {
        bf16x8 a0, a1;
        {
            float4 u0 = *reinterpret_cast<const float4*>(a0p + ks * 32);
            float4 u1 = *reinterpret_cast<const float4*>(a0p + ks * 32 + 4);
            float4 v0 = *reinterpret_cast<const float4*>(a1p + ks * 32);
            float4 v1 = *reinterpret_cast<const float4*>(a1p + ks * 32 + 4);
            a0[0] = (__bf16)u0.x; a0[1] = (__bf16)u0.y; a0[2] = (__bf16)u0.z; a0[3] = (__bf16)u0.w;
            a0[4] = (__bf16)u1.x; a0[5] = (__bf16)u1.y; a0[6] = (__bf16)u1.z; a0[7] = (__bf16)u1.w;
            a1[0] = (__bf16)v0.x; a1[1] = (__bf16)v0.y; a1[2] = (__bf16)v0.z; a1[3] = (__bf16)v0.w;
            a1[4] = (__bf16)v1.x; a1[5] = (__bf16)v1.y; a1[6] = (__bf16)v1.z; a1[7] = (__bf16)v1.w;
        }
        bf16x8 b[8];
#pragma unroll
        for (int n = 0; n < 8; ++n) b[n] = bbase[(ks * 8 + n) * 64];
#pragma unroll
        for (int n = 0; n < 8; ++n) {
            acc[0][n] = __builtin_amdgcn_mfma_f32_16x16x32_bf16(a0, b[n], acc[0][n], 0, 0, 0);
            acc[1][n] = __builtin_amdgcn_mfma_f32_16x16x32_bf16(a1, b[n], acc[1][n], 0, 0, 0);
        }
    }

    float bv[8];
#pragma unroll
    for (int n = 0; n < 8; ++n) bv[n] = bias[n * 16 + l15];

    // C/D layout: col = lane&15, row = (lane>>4)*4 + reg
#pragma unroll
    for (int mf = 0; mf < 2; ++mf) {
#pragma unroll
        for (int r = 0; r < 4; ++r) {
            int gr = rowbase + mf * 16 + kg * 4 + r;
            if (gr < M) {
                int orow = idx[gr];
                float* op = out + (size_t)orow * 128 + l15;
#pragma unroll
                for (int n = 0; n < 8; ++n) op[n * 16] = acc[mf][n][r] + bv[n];
            }
        }
    }
}

extern "C" void kernel_launch(void* const* d_in, const int* in_sizes, int n_in,
                              void* d_out, int out_size, void* d_ws, size_t ws_size,
                              hipStream_t stream) {
    const float* x0 = (const float*)d_in[0];
    const float* x1 = (const float*)d_in[1];
    const float* x2 = (const float*)d_in[2];
    const float* W0 = (const float*)d_in[3];
    const float* b0 = (const float*)d_in[4];
    const float* W1 = (const float*)d_in[5];
    const float* b1 = (const float*)d_in[6];
    const float* W2 = (const float*)d_in[7];
    const float* b2 = (const float*)d_in[8];
    const int* idx0 = (const int*)d_in[9];
    const int* idx1 = (const int*)d_in[10];
    const int* idx2 = (const int*)d_in[11];
    float* out = (float*)d_out;

    const int M0 = in_sizes[9];
    const int M1 = in_sizes[10];
    const int M2 = in_sizes[11];

    // ws layout: bf16 B-fragments for the three weight matrices
    __bf16* Bf0 = (__bf16*)d_ws;              // K=64:  2*8*64*8  =  8192 bf16
    __bf16* Bf1 = Bf0 + 2 * 8 * 64 * 8;       // K=128: 4*8*64*8  = 16384 bf16
    __bf16* Bf2 = Bf1 + 4 * 8 * 64 * 8;       // K=256: 8*8*64*8  = 32768 bf16

    {
        int t0 = 2 * 8 * 64, t1 = 4 * 8 * 64, t2 = 8 * 8 * 64;
        prep_w_kernel<<<(t0 + 255) / 256, 256, 0, stream>>>(W0, Bf0, 64, t0);
        prep_w_kernel<<<(t1 + 255) / 256, 256, 0, stream>>>(W1, Bf1, 128, t1);
        prep_w_kernel<<<(t2 + 255) / 256, 256, 0, stream>>>(W2, Bf2, 256, t2);
    }

    node_linear_kernel<64><<<(M0 + 127) / 128, 256, 0, stream>>>(x0, Bf0, b0, idx0, out, M0);
    node_linear_kernel<128><<<(M1 + 127) / 128, 256, 0, stream>>>(x1, Bf1, b1, idx1, out, M1);
    node_linear_kernel<256><<<(M2 + 127) / 128, 256, 0, stream>>>(x2, Bf2, b2, idx2, out, M2);
}

// Round 2
// 155.731 us; speedup vs baseline: 1.2478x; 1.2478x over previous
//
#include <hip/hip_runtime.h>

typedef __bf16 bf16x8 __attribute__((ext_vector_type(8)));
typedef float f32x4 __attribute__((ext_vector_type(4)));

// ---------------------------------------------------------------------------
// Repack all three W [H=128][K] fp32 -> bf16 MFMA B-fragments, one launch.
// Fragment layout: dst[((ks*8 + n)*64 + lane)*8 + e] =
//   bf16(W[n*16 + (lane&15)][ks*32 + (lane>>4)*8 + e])
// thread counts: K=64 -> 1024, K=128 -> 2048, K=256 -> 4096 (total 7168)
// ---------------------------------------------------------------------------
__global__ void prep_all_kernel(const float* __restrict__ W0, const float* __restrict__ W1,
                                const float* __restrict__ W2,
                                __bf16* __restrict__ Bf0, __bf16* __restrict__ Bf1,
                                __bf16* __restrict__ Bf2) {
    int t = blockIdx.x * blockDim.x + threadIdx.x;
    const float* W;
    __bf16* dst;
    int K;
    if (t < 1024)      { W = W0; dst = Bf0; K = 64; }
    else if (t < 3072) { W = W1; dst = Bf1; K = 128; t -= 1024; }
    else if (t < 7168) { W = W2; dst = Bf2; K = 256; t -= 3072; }
    else return;
    int lane = t & 63;
    int n = (t >> 6) & 7;
    int ks = t >> 9;
    int row = n * 16 + (lane & 15);
    int k0 = ks * 32 + ((lane >> 4) << 3);
    const float* src = W + (size_t)row * K + k0;
    __bf16* d = dst + (size_t)t * 8;
#pragma unroll
    for (int e = 0; e < 8; ++e) d[e] = (__bf16)src[e];
}

// ---------------------------------------------------------------------------
// One block = 256 threads = 4 waves; block computes 128 rows x 128 cols.
// Each wave: 32 rows (2 M-frags) x 128 cols (8 N-frags), 16x16x32 bf16 MFMA.
// ---------------------------------------------------------------------------
template <int K>
__device__ __forceinline__ void run_type(
    const float* __restrict__ x, const __bf16* __restrict__ Bfrag,
    const float* __restrict__ bias, const int* __restrict__ idx,
    float* __restrict__ out, int M, int blk)
{
    constexpr int KSTEPS = K / 32;
    const int lane = threadIdx.x & 63;
    const int wave = threadIdx.x >> 6;
    const int l15 = lane & 15;
    const int kg = lane >> 4;
    const int rowbase = blk * 128 + wave * 32;

    f32x4 acc[2][8] = {};

    int r0 = rowbase + l15;
    int r1 = r0 + 16;
    int r0c = r0 < M ? r0 : M - 1;
    int r1c = r1 < M ? r1 : M - 1;
    const float* a0p = x + (size_t)r0c * K + kg * 8;
    const float* a1p = x + (size_t)r1c * K + kg * 8;
    const bf16x8* bbase = reinterpret_cast<const bf16x8*>(Bfrag) + lane;

#pragma unroll
    for (int ks = 0; ks < KSTEPS; ++ks) {
        bf16x8 a0, a1;
        {
            float4 u0 = *reinterpret_cast<const float4*>(a0p + ks * 32);
            float4 u1 = *reinterpret_cast<const float4*>(a0p + ks * 32 + 4);
            float4 v0 = *reinterpret_cast<const float4*>(a1p + ks * 32);
            float4 v1 = *reinterpret_cast<const float4*>(a1p + ks * 32 + 4);
            a0[0] = (__bf16)u0.x; a0[1] = (__bf16)u0.y; a0[2] = (__bf16)u0.z; a0[3] = (__bf16)u0.w;
            a0[4] = (__bf16)u1.x; a0[5] = (__bf16)u1.y; a0[6] = (__bf16)u1.z; a0[7] = (__bf16)u1.w;
            a1[0] = (__bf16)v0.x; a1[1] = (__bf16)v0.y; a1[2] = (__bf16)v0.z; a1[3] = (__bf16)v0.w;
            a1[4] = (__bf16)v1.x; a1[5] = (__bf16)v1.y; a1[6] = (__bf16)v1.z; a1[7] = (__bf16)v1.w;
        }
        bf16x8 b[8];
#pragma unroll
        for (int n = 0; n < 8; ++n) b[n] = bbase[(ks * 8 + n) * 64];
#pragma unroll
        for (int n = 0; n < 8; ++n) {
            acc[0][n] = __builtin_amdgcn_mfma_f32_16x16x32_bf16(a0, b[n], acc[0][n], 0, 0, 0);
            acc[1][n] = __builtin_amdgcn_mfma_f32_16x16x32_bf16(a1, b[n], acc[1][n], 0, 0, 0);
        }
    }

    float bv[8];
#pragma unroll
    for (int n = 0; n < 8; ++n) bv[n] = bias[n * 16 + l15];

    // C/D layout: col = lane&15, row = (lane>>4)*4 + reg
#pragma unroll
    for (int mf = 0; mf < 2; ++mf) {
#pragma unroll
        for (int r = 0; r < 4; ++r) {
            int gr = rowbase + mf * 16 + kg * 4 + r;
            if (gr < M) {
                int orow = idx[gr];
                float* op = out + (size_t)orow * 128 + l15;
#pragma unroll
                for (int n = 0; n < 8; ++n) op[n * 16] = acc[mf][n][r] + bv[n];
            }
        }
    }
}

// Fused: one grid covers all three types. Longest-K type first (better tail).
__global__ __launch_bounds__(256, 3) void fused_linear_kernel(
    const float* __restrict__ x0, const float* __restrict__ x1, const float* __restrict__ x2,
    const __bf16* __restrict__ Bf0, const __bf16* __restrict__ Bf1, const __bf16* __restrict__ Bf2,
    const float* __restrict__ b0, const float* __restrict__ b1, const float* __restrict__ b2,
    const int* __restrict__ idx0, const int* __restrict__ idx1, const int* __restrict__ idx2,
    float* __restrict__ out, int M0, int M1, int M2, int nb2, int nb21)
{
    int b = blockIdx.x;
    if (b < nb2)       run_type<256>(x2, Bf2, b2, idx2, out, M2, b);
    else if (b < nb21) run_type<128>(x1, Bf1, b1, idx1, out, M1, b - nb2);
    else               run_type<64>(x0, Bf0, b0, idx0, out, M0, b - nb21);
}

extern "C" void kernel_launch(void* const* d_in, const int* in_sizes, int n_in,
                              void* d_out, int out_size, void* d_ws, size_t ws_size,
                              hipStream_t stream) {
    const float* x0 = (const float*)d_in[0];
    const float* x1 = (const float*)d_in[1];
    const float* x2 = (const float*)d_in[2];
    const float* W0 = (const float*)d_in[3];
    const float* b0 = (const float*)d_in[4];
    const float* W1 = (const float*)d_in[5];
    const float* b1 = (const float*)d_in[6];
    const float* W2 = (const float*)d_in[7];
    const float* b2 = (const float*)d_in[8];
    const int* idx0 = (const int*)d_in[9];
    const int* idx1 = (const int*)d_in[10];
    const int* idx2 = (const int*)d_in[11];
    float* out = (float*)d_out;

    const int M0 = in_sizes[9];
    const int M1 = in_sizes[10];
    const int M2 = in_sizes[11];

    __bf16* Bf0 = (__bf16*)d_ws;              // K=64:  8192 bf16
    __bf16* Bf1 = Bf0 + 2 * 8 * 64 * 8;       // K=128: 16384 bf16
    __bf16* Bf2 = Bf1 + 4 * 8 * 64 * 8;       // K=256: 32768 bf16

    prep_all_kernel<<<(7168 + 255) / 256, 256, 0, stream>>>(W0, W1, W2, Bf0, Bf1, Bf2);

    const int nb0 = (M0 + 127) / 128;
    const int nb1 = (M1 + 127) / 128;
    const int nb2 = (M2 + 127) / 128;
    fused_linear_kernel<<<nb0 + nb1 + nb2, 256, 0, stream>>>(
        x0, x1, x2, Bf0, Bf1, Bf2, b0, b1, b2, idx0, idx1, idx2,
        out, M0, M1, M2, nb2, nb2 + nb1);
}